// Round 6
// baseline (253.334 us; speedup 1.0000x reference)
//
#include <hip/hip_runtime.h>
#include <hip/hip_bf16.h>
#include <math.h>

typedef __bf16 bf16x8 __attribute__((ext_vector_type(8)));
typedef __bf16 bf16x4 __attribute__((ext_vector_type(4)));
typedef float f32x4 __attribute__((ext_vector_type(4)));

#define N_TOK 4096
#define EDIM 512
#define NHEAD 8
#define HD 64
#define LDQKV 1536
#define LDCOMB 896
#define NBIN 100
#define SPLITK 8
#define BK 64

// ---------------- fp32 -> bf16 convert, 3 arrays fused ----------------
__global__ void cvt4_kernel(const float* __restrict__ s0, __bf16* __restrict__ d0, int n0,
                            const float* __restrict__ s1, __bf16* __restrict__ d1, int n1,
                            const float* __restrict__ s2, __bf16* __restrict__ d2, int n2) {
    int i = blockIdx.x * blockDim.x + threadIdx.x;
    const float* src; __bf16* dst;
    if (i < n0)                { src = s0; dst = d0; }
    else if (i < n0 + n1)      { i -= n0; src = s1; dst = d1; }
    else if (i < n0 + n1 + n2) { i -= n0 + n1; src = s2; dst = d2; }
    else return;
    const float4 v = ((const float4*)src)[i];
    bf16x4 o;
    o[0] = (__bf16)v.x; o[1] = (__bf16)v.y; o[2] = (__bf16)v.z; o[3] = (__bf16)v.w;
    ((bf16x4*)dst)[i] = o;
}

// ---------------- transpose+convert w_out: wt[k][m] = w[m][k], bf16 ----------------
__global__ __launch_bounds__(256) void tc_kernel(const float* __restrict__ w,
                                                 __bf16* __restrict__ wt) {
    __shared__ float T[64][65];
    const int m0 = blockIdx.x * 64, k0 = blockIdx.y * 64;
    const int tid = threadIdx.x;
    const int row = tid >> 2, c4 = (tid & 3) * 16;
    #pragma unroll
    for (int i = 0; i < 4; i++) {
        const float4 v = *(const float4*)&w[(size_t)(m0 + row) * EDIM + k0 + c4 + i * 4];
        T[row][c4 + i * 4 + 0] = v.x;
        T[row][c4 + i * 4 + 1] = v.y;
        T[row][c4 + i * 4 + 2] = v.z;
        T[row][c4 + i * 4 + 3] = v.w;
    }
    __syncthreads();
    const int kr = tid >> 2, m16 = (tid & 3) * 16;
    bf16x8 o0, o1;
    #pragma unroll
    for (int i = 0; i < 8; i++) o0[i] = (__bf16)T[m16 + i][kr];
    #pragma unroll
    for (int i = 0; i < 8; i++) o1[i] = (__bf16)T[m16 + 8 + i][kr];
    *(bf16x8*)&wt[(size_t)(k0 + kr) * EDIM + m0 + m16] = o0;
    *(bf16x8*)&wt[(size_t)(k0 + kr) * EDIM + m0 + m16 + 8] = o1;
}

// ---------------- generic NT bf16 MFMA GEMM: C = A * B^T (+ bias) ----------------
template<int OUT_MODE>
__global__ __launch_bounds__(256) void gemm_nt(const __bf16* __restrict__ A, int lda,
                                               const __bf16* __restrict__ B, int ldb,
                                               const float* __restrict__ bias,
                                               void* __restrict__ C, int ldc,
                                               int K) {
    __shared__ __attribute__((aligned(16))) __bf16 As[128][40];
    __shared__ __attribute__((aligned(16))) __bf16 Bs[128][40];
    const int tid = threadIdx.x;
    const int wave = tid >> 6, lane = tid & 63;
    const int wm = (wave >> 1) * 64, wn = (wave & 1) * 64;
    const int bm = blockIdx.x * 128, bn = blockIdx.y * 128;
    const int lr = lane & 15, lq = lane >> 4;

    f32x4 acc[4][4] = {};

    for (int k0 = 0; k0 < K; k0 += 32) {
        __syncthreads();
        #pragma unroll
        for (int c = tid; c < 512; c += 256) {
            const int row = c >> 2, k8 = (c & 3) * 8;
            *(bf16x8*)&As[row][k8] = *(const bf16x8*)&A[(size_t)(bm + row) * lda + k0 + k8];
            *(bf16x8*)&Bs[row][k8] = *(const bf16x8*)&B[(size_t)(bn + row) * ldb + k0 + k8];
        }
        __syncthreads();
        bf16x8 af[4], bfr[4];
        #pragma unroll
        for (int i = 0; i < 4; i++) {
            af[i]  = *(const bf16x8*)&As[wm + i * 16 + lr][lq * 8];
            bfr[i] = *(const bf16x8*)&Bs[wn + i * 16 + lr][lq * 8];
        }
        #pragma unroll
        for (int i = 0; i < 4; i++)
            #pragma unroll
            for (int j = 0; j < 4; j++)
                acc[i][j] = __builtin_amdgcn_mfma_f32_16x16x32_bf16(af[i], bfr[j], acc[i][j], 0, 0, 0);
    }

    #pragma unroll
    for (int i = 0; i < 4; i++) {
        #pragma unroll
        for (int j = 0; j < 4; j++) {
            const int col = bn + wn + j * 16 + lr;
            float bv = 0.f;
            if (bias) bv = bias[col];
            #pragma unroll
            for (int r = 0; r < 4; r++) {
                const int row = bm + wm + i * 16 + lq * 4 + r;
                const float v = acc[i][j][r] + bv;
                if (OUT_MODE == 0) ((float*)C)[(size_t)row * ldc + col] = v;
                else               ((__bf16*)C)[(size_t)row * ldc + col] = (__bf16)v;
            }
        }
    }
}

// ---------------- fused final GEMM: h = ctx @ weff^T + add2[dmask] + tv[step] ----------------
__global__ __launch_bounds__(256) void gemm_fused(const __bf16* __restrict__ A,
                                                  const __bf16* __restrict__ B,
                                                  const int* __restrict__ dmask,
                                                  const int* __restrict__ steps,
                                                  const float* __restrict__ add2,
                                                  const float* __restrict__ tv,
                                                  float* __restrict__ C) {
    __shared__ __attribute__((aligned(16))) __bf16 As[128][40];
    __shared__ __attribute__((aligned(16))) __bf16 Bs[128][40];
    const int tid = threadIdx.x;
    const int wave = tid >> 6, lane = tid & 63;
    const int wm = (wave >> 1) * 64, wn = (wave & 1) * 64;
    const int bm = blockIdx.x * 128, bn = blockIdx.y * 128;
    const int lr = lane & 15, lq = lane >> 4;

    f32x4 acc[4][4] = {};

    for (int k0 = 0; k0 < EDIM; k0 += 32) {
        __syncthreads();
        #pragma unroll
        for (int c = tid; c < 512; c += 256) {
            const int row = c >> 2, k8 = (c & 3) * 8;
            *(bf16x8*)&As[row][k8] = *(const bf16x8*)&A[(size_t)(bm + row) * EDIM + k0 + k8];
            *(bf16x8*)&Bs[row][k8] = *(const bf16x8*)&B[(size_t)(bn + row) * EDIM + k0 + k8];
        }
        __syncthreads();
        bf16x8 af[4], bfr[4];
        #pragma unroll
        for (int i = 0; i < 4; i++) {
            af[i]  = *(const bf16x8*)&As[wm + i * 16 + lr][lq * 8];
            bfr[i] = *(const bf16x8*)&Bs[wn + i * 16 + lr][lq * 8];
        }
        #pragma unroll
        for (int i = 0; i < 4; i++)
            #pragma unroll
            for (int j = 0; j < 4; j++)
                acc[i][j] = __builtin_amdgcn_mfma_f32_16x16x32_bf16(af[i], bfr[j], acc[i][j], 0, 0, 0);
    }

    int dmr[4][4], str[4][4];
    #pragma unroll
    for (int i = 0; i < 4; i++)
        #pragma unroll
        for (int r = 0; r < 4; r++) {
            const int row = bm + wm + i * 16 + lq * 4 + r;
            dmr[i][r] = dmask[row];
            str[i][r] = min(max(steps[row], 0), NBIN - 1);
        }
    #pragma unroll
    for (int i = 0; i < 4; i++) {
        #pragma unroll
        for (int j = 0; j < 4; j++) {
            const int col = bn + wn + j * 16 + lr;
            #pragma unroll
            for (int r = 0; r < 4; r++) {
                const int row = bm + wm + i * 16 + lq * 4 + r;
                const float v = acc[i][j][r] + add2[dmr[i][r] * EDIM + col]
                              + tv[str[i][r] * EDIM + col];
                C[(size_t)row * EDIM + col] = v;
            }
        }
    }
}

// ---------------- add2[m][j] = status_embed[m] . w_mlp[j,512:640] + bias_eff[j] ----------------
__global__ __launch_bounds__(256) void addvec_kernel(const float* __restrict__ status,
                                                     const float* __restrict__ w_mlp,
                                                     const float* __restrict__ out_b,
                                                     const float* __restrict__ mlp_b,
                                                     float* __restrict__ add2) {
    const int j = blockIdx.x * 256 + threadIdx.x;   // 0..511
    const float* wr = w_mlp + (size_t)j * LDCOMB;
    float b = mlp_b[j];
    for (int k = 0; k < EDIM; k++) b += wr[k] * out_b[k];
    float s0 = 0.f, s1 = 0.f;
    for (int c = 0; c < 128; c++) {
        const float w = wr[EDIM + c];
        s0 += status[c] * w;
        s1 += status[128 + c] * w;
    }
    add2[j] = s0 + b;
    add2[EDIM + j] = s1 + b;
}

// ---------------- tv[st][j] = time_enc[st] . w_mlp[j,640:896] (fp32 exact) ----------------
__global__ __launch_bounds__(128) void tv_kernel(const float* __restrict__ w_mlp,
                                                 float* __restrict__ tv) {
    __shared__ float sn[128], cs[128];
    const int st = blockIdx.x;
    const int t = threadIdx.x;
    {
        const float div = expf((float)(2 * t) * (-9.210340371976184f / 256.0f));
        const float ang = (float)st * div;
        sn[t] = sinf(ang);
        cs[t] = cosf(ang);
    }
    __syncthreads();
    const int j = blockIdx.y * 128 + t;
    const float* wr = w_mlp + (size_t)j * LDCOMB + 640;
    float acc = 0.f;
    #pragma unroll 4
    for (int p = 0; p < 128; p++)
        acc += sn[p] * wr[2 * p] + cs[p] * wr[2 * p + 1];
    tv[st * EDIM + j] = acc;
}

// ---------------- counting sort by step (100 bins), single block ----------------
__global__ __launch_bounds__(1024) void sort_kernel(const int* __restrict__ steps,
                                                    int* __restrict__ perm,
                                                    int* __restrict__ sstep,
                                                    int* __restrict__ bin_start) {
    __shared__ int hist[NBIN];
    __shared__ int offs[NBIN];
    const int tid = threadIdx.x;
    if (tid < NBIN) hist[tid] = 0;
    __syncthreads();
    for (int i = tid; i < N_TOK; i += 1024)
        atomicAdd(&hist[min(max(steps[i], 0), NBIN - 1)], 1);
    __syncthreads();
    if (tid == 0) {
        int acc = 0;
        for (int s = 0; s < NBIN; s++) { offs[s] = acc; acc += hist[s]; }
    }
    __syncthreads();
    if (tid < NBIN) bin_start[tid] = offs[tid];
    __syncthreads();
    for (int i = tid; i < N_TOK; i += 1024) {
        const int s = min(max(steps[i], 0), NBIN - 1);
        const int pos = atomicAdd(&offs[s], 1);
        perm[pos] = i;
        sstep[pos] = s;
    }
}

// ---------------- gather sorted Q (prescaled), K compact, V^T ----------------
__global__ __launch_bounds__(256) void gather_kernel(const __bf16* __restrict__ qkv,
                                                     const int* __restrict__ perm,
                                                     __bf16* __restrict__ qs,
                                                     __bf16* __restrict__ ks,
                                                     __bf16* __restrict__ vt) {
    __shared__ __attribute__((aligned(16))) __bf16 T[64][72];
    __shared__ int pr[64];
    const int h = blockIdx.y;
    const int n0 = blockIdx.x * 64;
    const int tid = threadIdx.x;
    if (tid < 64) pr[tid] = perm[n0 + tid];
    __syncthreads();
    const float SC = 0.125f * 1.44269504f;   // 1/sqrt(64) * log2(e)
    #pragma unroll
    for (int c = tid; c < 512; c += 256) {
        const int r = c >> 3, d8 = (c & 7) * 8;
        const size_t src = (size_t)pr[r] * LDQKV + h * HD + d8;
        bf16x8 q = *(const bf16x8*)&qkv[src];
        #pragma unroll
        for (int j = 0; j < 8; j++) q[j] = (__bf16)((float)q[j] * SC);
        *(bf16x8*)&qs[(size_t)(n0 + r) * EDIM + h * HD + d8] = q;
        *(bf16x8*)&ks[(size_t)(n0 + r) * EDIM + h * HD + d8] =
            *(const bf16x8*)&qkv[src + EDIM];
        *(bf16x8*)&T[r][d8] = *(const bf16x8*)&qkv[src + 2 * EDIM];
    }
    __syncthreads();
    #pragma unroll
    for (int c = tid; c < 512; c += 256) {
        const int d = c & 63, k8 = (c >> 6) * 8;
        bf16x8 v;
        #pragma unroll
        for (int j = 0; j < 8; j++) v[j] = T[k8 + j][d];
        *(bf16x8*)&vt[(size_t)(h * HD + d) * N_TOK + n0 + k8] = v;
    }
}

// ---------------- flash attention: sorted, split-K=8, LDS-staged, reg-prefetch ----------------
__global__ __launch_bounds__(256) void attn_kernel(const __bf16* __restrict__ qs,
                                                   const __bf16* __restrict__ ks,
                                                   const __bf16* __restrict__ vt,
                                                   const int* __restrict__ sstep,
                                                   const int* __restrict__ bin_start,
                                                   __bf16* __restrict__ po,
                                                   float* __restrict__ pl) {
    __shared__ __attribute__((aligned(16))) __bf16 Ks[BK][72];     // [key][d]
    __shared__ __attribute__((aligned(16))) __bf16 Vs[64][BK + 8]; // [d][key]
    __shared__ __attribute__((aligned(16))) __bf16 Ps[64][BK + 8]; // [q][key] wave bands

    const int h = blockIdx.y;
    const int qtile = blockIdx.x;
    const int ck = blockIdx.z;
    const int tid = threadIdx.x, wave = tid >> 6, lane = tid & 63;
    const int lr = lane & 15, lq = lane >> 4;
    const int qbase = qtile * 64 + wave * 16;

    const int kt0 = bin_start[sstep[qtile * 64]] & ~(BK - 1);
    const int nt = (N_TOK - kt0) / BK;
    const int kta = kt0 + ((nt * ck) / SPLITK) * BK;
    const int ktb = kt0 + ((nt * (ck + 1)) / SPLITK) * BK;
    const int bs_blockmax = bin_start[sstep[qtile * 64 + 63]];

    bf16x8 aq[2];
    {
        const __bf16* qrow = qs + (size_t)(qbase + lr) * EDIM + h * HD;
        aq[0] = *(const bf16x8*)&qrow[lq * 8];
        aq[1] = *(const bf16x8*)&qrow[32 + lq * 8];
    }
    int bs_r[4];
    #pragma unroll
    for (int r = 0; r < 4; r++) bs_r[r] = bin_start[sstep[qbase + lq * 4 + r]];

    float l_i[4] = {0.f, 0.f, 0.f, 0.f};
    f32x4 o[4] = {};

    const __bf16* kbase = ks + h * HD;
    const __bf16* vbase = vt + (size_t)h * HD * N_TOK;

    // staging assignment: each thread stages 2 K rows + 2 V rows
    const int r0 = tid >> 3, r1 = r0 + 32, k8 = (tid & 7) * 8;
    bf16x8 kr0, kr1, vr0, vr1;
    if (kta < ktb) {
        kr0 = *(const bf16x8*)&kbase[(size_t)(kta + r0) * EDIM + k8];
        kr1 = *(const bf16x8*)&kbase[(size_t)(kta + r1) * EDIM + k8];
        vr0 = *(const bf16x8*)&vbase[(size_t)r0 * N_TOK + kta + k8];
        vr1 = *(const bf16x8*)&vbase[(size_t)r1 * N_TOK + kta + k8];
    }

    for (int kt = kta; kt < ktb; kt += BK) {
        __syncthreads();
        *(bf16x8*)&Ks[r0][k8] = kr0;
        *(bf16x8*)&Ks[r1][k8] = kr1;
        *(bf16x8*)&Vs[r0][k8] = vr0;
        *(bf16x8*)&Vs[r1][k8] = vr1;
        __syncthreads();
        // prefetch next tile into registers (overlaps with compute below)
        if (kt + BK < ktb) {
            kr0 = *(const bf16x8*)&kbase[(size_t)(kt + BK + r0) * EDIM + k8];
            kr1 = *(const bf16x8*)&kbase[(size_t)(kt + BK + r1) * EDIM + k8];
            vr0 = *(const bf16x8*)&vbase[(size_t)r0 * N_TOK + kt + BK + k8];
            vr1 = *(const bf16x8*)&vbase[(size_t)r1 * N_TOK + kt + BK + k8];
        }

        // S = Q K^T
        f32x4 s[4];
        #pragma unroll
        for (int t = 0; t < 4; t++) {
            bf16x8 b0 = *(const bf16x8*)&Ks[t * 16 + lr][lq * 8];
            bf16x8 b1 = *(const bf16x8*)&Ks[t * 16 + lr][32 + lq * 8];
            f32x4 a = {};
            a = __builtin_amdgcn_mfma_f32_16x16x32_bf16(aq[0], b0, a, 0, 0, 0);
            a = __builtin_amdgcn_mfma_f32_16x16x32_bf16(aq[1], b1, a, 0, 0, 0);
            s[t] = a;
        }
        // position-based mask (uniform branch outside boundary region)
        if (kt < bs_blockmax) {
            #pragma unroll
            for (int t = 0; t < 4; t++) {
                const int col = kt + t * 16 + lr;
                #pragma unroll
                for (int r = 0; r < 4; r++)
                    if (col < bs_r[r]) s[t][r] = -1e9f;
            }
        }
        // p = exp2(s); accumulate denominator; write P band
        #pragma unroll
        for (int t = 0; t < 4; t++) {
            #pragma unroll
            for (int r = 0; r < 4; r++) {
                const float p = exp2f(s[t][r]);
                l_i[r] += p;
                Ps[wave * 16 + lq * 4 + r][t * 16 + lr] = (__bf16)p;
            }
        }
        // O += P V
        #pragma unroll
        for (int ks2 = 0; ks2 < 2; ks2++) {
            bf16x8 ap = *(const bf16x8*)&Ps[wave * 16 + lr][ks2 * 32 + lq * 8];
            #pragma unroll
            for (int dt = 0; dt < 4; dt++) {
                bf16x8 bv = *(const bf16x8*)&Vs[dt * 16 + lr][ks2 * 32 + lq * 8];
                o[dt] = __builtin_amdgcn_mfma_f32_16x16x32_bf16(ap, bv, o[dt], 0, 0, 0);
            }
        }
    }

    #pragma unroll
    for (int r = 0; r < 4; r++) {
        float v = l_i[r];
        v += __shfl_xor(v, 1);
        v += __shfl_xor(v, 2);
        v += __shfl_xor(v, 4);
        v += __shfl_xor(v, 8);
        l_i[r] = v;
    }
    __bf16* pob = po + (((size_t)(ck * NHEAD + h) * N_TOK) + qbase) * HD;
    #pragma unroll
    for (int dt = 0; dt < 4; dt++)
        #pragma unroll
        for (int r = 0; r < 4; r++)
            pob[(lq * 4 + r) * HD + dt * 16 + lr] = (__bf16)o[dt][r];
    if (lr == 0) {
        #pragma unroll
        for (int r = 0; r < 4; r++)
            pl[(size_t)(ck * NHEAD + h) * N_TOK + qbase + lq * 4 + r] = l_i[r];
    }
}

// ---------------- combine split-K partials, normalize, scatter to ctx ----------------
__global__ __launch_bounds__(256) void combine_kernel(const __bf16* __restrict__ po,
                                                      const float* __restrict__ pl,
                                                      const int* __restrict__ perm,
                                                      __bf16* __restrict__ ctx) {
    const int e = blockIdx.x * 256 + threadIdx.x;   // over 4096*512
    const int q = e >> 9;
    const int col = e & 511;
    const int h = col >> 6, d = col & 63;
    float s = 0.f, l = 0.f;
    #pragma unroll
    for (int c = 0; c < SPLITK; c++) {
        s += (float)po[(((size_t)(c * NHEAD + h) * N_TOK) + q) * HD + d];
        l += pl[(size_t)(c * NHEAD + h) * N_TOK + q];
    }
    ctx[(size_t)perm[q] * EDIM + col] = (__bf16)(s / l);
}

// ---------------- LayerNorm + ReLU + residual ----------------
__global__ __launch_bounds__(256) void ln_kernel(const float* __restrict__ h,
                                                 const float* __restrict__ x,
                                                 const float* __restrict__ gamma,
                                                 const float* __restrict__ beta,
                                                 float* __restrict__ out) {
    const int row = blockIdx.x * 4 + (threadIdx.x >> 6);
    const int lane = threadIdx.x & 63;
    const float* hr = h + (size_t)row * EDIM;
    float4 v0 = ((const float4*)hr)[lane];
    float4 v1 = ((const float4*)hr)[64 + lane];
    float sum = v0.x + v0.y + v0.z + v0.w + v1.x + v1.y + v1.z + v1.w;
    float sq = v0.x * v0.x + v0.y * v0.y + v0.z * v0.z + v0.w * v0.w +
               v1.x * v1.x + v1.y * v1.y + v1.z * v1.z + v1.w * v1.w;
    #pragma unroll
    for (int m = 1; m < 64; m <<= 1) {
        sum += __shfl_xor(sum, m);
        sq  += __shfl_xor(sq, m);
    }
    const float mean = sum * (1.0f / EDIM);
    const float var = sq * (1.0f / EDIM) - mean * mean;
    const float rstd = rsqrtf(var + 1e-5f);
    const float* xr = x + (size_t)row * EDIM;
    float* orow = out + (size_t)row * EDIM;
    #pragma unroll
    for (int half = 0; half < 2; half++) {
        const float4 v = half ? v1 : v0;
        const int cb = half * 256 + lane * 4;
        float4 res;
        const float* vp = (const float*)&v;
        float tmp[4];
        #pragma unroll
        for (int i = 0; i < 4; i++) {
            const int c = cb + i;
            float t = (vp[i] - mean) * rstd * gamma[c] + beta[c];
            t = fmaxf(t, 0.f);
            tmp[i] = xr[c] + t;
        }
        res.x = tmp[0]; res.y = tmp[1]; res.z = tmp[2]; res.w = tmp[3];
        ((float4*)orow)[cb >> 2] = res;
    }
}

// ---------------- launch ----------------
extern "C" void kernel_launch(void* const* d_in, const int* in_sizes, int n_in,
                              void* d_out, int out_size, void* d_ws, size_t ws_size,
                              hipStream_t stream) {
    const float* x      = (const float*)d_in[0];
    const int*   dmask  = (const int*)d_in[1];
    const int*   steps  = (const int*)d_in[2];
    const float* status = (const float*)d_in[3];
    const float* w_in   = (const float*)d_in[4];
    const float* b_in   = (const float*)d_in[5];
    const float* w_out  = (const float*)d_in[6];
    const float* b_out  = (const float*)d_in[7];
    const float* w_mlp  = (const float*)d_in[8];
    const float* b_mlp  = (const float*)d_in[9];
    const float* gamma  = (const float*)d_in[10];
    const float* beta   = (const float*)d_in[11];
    float* out = (float*)d_out;

    char* ws = (char*)d_ws;
    size_t off = 0;
    auto alloc = [&](size_t bytes) {
        void* p = ws + off;
        off = (off + bytes + 255) & ~(size_t)255;
        return p;
    };
    __bf16* x_bf    = (__bf16*)alloc((size_t)N_TOK * EDIM * 2);   // reused as qs
    __bf16* wqkv_bf = (__bf16*)alloc((size_t)3 * EDIM * EDIM * 2);
    __bf16* wmlp_bf = (__bf16*)alloc((size_t)EDIM * LDCOMB * 2);
    __bf16* woutT_bf= (__bf16*)alloc((size_t)EDIM * EDIM * 2);
    __bf16* weff_bf = (__bf16*)alloc((size_t)EDIM * EDIM * 2);
    __bf16* qkv_bf  = (__bf16*)alloc((size_t)N_TOK * LDQKV * 2);
    __bf16* ks_bf   = (__bf16*)alloc((size_t)N_TOK * EDIM * 2);
    __bf16* vt_bf   = (__bf16*)alloc((size_t)EDIM * N_TOK * 2);
    __bf16* ctx_bf  = (__bf16*)alloc((size_t)N_TOK * EDIM * 2);
    float*  h_f32   = (float*)alloc((size_t)N_TOK * EDIM * 4);
    int*    perm    = (int*)alloc(N_TOK * 4);
    int*    sstep   = (int*)alloc(N_TOK * 4);
    int*    binst   = (int*)alloc(NBIN * 4);
    __bf16* po      = (__bf16*)alloc((size_t)SPLITK * NHEAD * N_TOK * HD * 2);
    float*  pl      = (float*)alloc((size_t)SPLITK * NHEAD * N_TOK * 4);
    float*  add2    = (float*)alloc(2 * EDIM * 4);
    float*  tv      = (float*)alloc((size_t)NBIN * EDIM * 4);
    __bf16* qs_bf   = x_bf;   // alias: x_bf dead after qkv GEMM

    // converts (x, w_in, w_mlp)
    {
        const int n0 = N_TOK * EDIM / 4;
        const int n1 = 3 * EDIM * EDIM / 4;
        const int n2 = EDIM * LDCOMB / 4;
        const int tot = n0 + n1 + n2;
        cvt4_kernel<<<(tot + 255) / 256, 256, 0, stream>>>(
            x, x_bf, n0, w_in, wqkv_bf, n1, w_mlp, wmlp_bf, n2);
    }
    // transpose+convert w_out
    tc_kernel<<<dim3(8, 8), 256, 0, stream>>>(w_out, woutT_bf);
    // w_eff = w_mlp[:, :512] @ w_out   (bf16, [512][512])
    gemm_nt<1><<<dim3(4, 4), 256, 0, stream>>>(
        wmlp_bf, LDCOMB, woutT_bf, EDIM, nullptr, weff_bf, EDIM, EDIM);
    // add2 (status+bias) and tv (time) precomputes, fp32 exact
    addvec_kernel<<<2, 256, 0, stream>>>(status, w_mlp, b_out, b_mlp, add2);
    tv_kernel<<<dim3(NBIN, 4), 128, 0, stream>>>(w_mlp, tv);
    // qkv = x @ w_in^T + b_in
    gemm_nt<1><<<dim3(N_TOK / 128, 3 * EDIM / 128), 256, 0, stream>>>(
        x_bf, EDIM, wqkv_bf, EDIM, b_in, qkv_bf, LDQKV, EDIM);
    // counting sort by step
    sort_kernel<<<1, 1024, 0, stream>>>(steps, perm, sstep, binst);
    // gather sorted Q/K/V^T
    gather_kernel<<<dim3(N_TOK / 64, NHEAD), 256, 0, stream>>>(qkv_bf, perm, qs_bf, ks_bf, vt_bf);
    // attention (split-K=8, LDS-staged, prefetch)
    attn_kernel<<<dim3(N_TOK / 64, NHEAD, SPLITK), 256, 0, stream>>>(
        qs_bf, ks_bf, vt_bf, sstep, binst, po, pl);
    // combine partials -> ctx (original token order)
    combine_kernel<<<(N_TOK * EDIM) / 256, 256, 0, stream>>>(po, pl, perm, ctx_bf);
    // h = ctx @ w_eff^T + add2[dmask] + tv[step]
    gemm_fused<<<dim3(N_TOK / 128, EDIM / 128), 256, 0, stream>>>(
        ctx_bf, weff_bf, dmask, steps, add2, tv, h_f32);
    // LN + ReLU + residual
    ln_kernel<<<N_TOK / 4, 256, 0, stream>>>(h_f32, x, gamma, beta, out);
}

// Round 7
// 229.293 us; speedup vs baseline: 1.1048x; 1.1048x over previous
//
#include <hip/hip_runtime.h>
#include <hip/hip_bf16.h>
#include <math.h>

typedef __bf16 bf16x8 __attribute__((ext_vector_type(8)));
typedef __bf16 bf16x4 __attribute__((ext_vector_type(4)));
typedef float f32x4 __attribute__((ext_vector_type(4)));

#define N_TOK 4096
#define EDIM 512
#define NHEAD 8
#define HD 64
#define LDQKV 1536
#define LDCOMB 896
#define NBIN 100
#define SPLITK 8
#define BK 64
#define NWORK (64 * NHEAD * SPLITK)

// prep block partition
#define NB_CVT 3264
#define NB_TC 64
#define NB_ADD 128
#define NB_TV 200
#define NB_PREP (NB_CVT + NB_TC + NB_ADD + NB_TV + 1)

// ---------------- prep mega-kernel: cvt + w_out transpose + addvec + tv + sort ----------------
__global__ __launch_bounds__(256) void prep_kernel(
    const float* __restrict__ x, const float* __restrict__ w_in,
    const float* __restrict__ w_mlp, const float* __restrict__ w_out,
    const float* __restrict__ status, const float* __restrict__ out_b,
    const float* __restrict__ mlp_b, const int* __restrict__ steps,
    __bf16* __restrict__ x_bf, __bf16* __restrict__ wqkv_bf,
    __bf16* __restrict__ wmlp_bf, __bf16* __restrict__ woutT_bf,
    float* __restrict__ add2, float* __restrict__ tv,
    int* __restrict__ perm, int* __restrict__ sstep, int* __restrict__ bin_start,
    int* __restrict__ workctr) {
    __shared__ float T[64][65];
    __shared__ int hist[NBIN];
    __shared__ int offs[NBIN];
    __shared__ float sn[128], cs[128];
    const int bid = blockIdx.x;
    const int tid = threadIdx.x;

    if (bid < NB_CVT) {
        // fp32 -> bf16 converts: x, w_in, w_mlp
        int i = bid * 256 + tid;
        const int n0 = N_TOK * EDIM / 4;
        const int n1 = 3 * EDIM * EDIM / 4;
        const float* src; __bf16* dst;
        if (i < n0)           { src = x; dst = x_bf; }
        else if (i < n0 + n1) { i -= n0; src = w_in; dst = wqkv_bf; }
        else                  { i -= n0 + n1; src = w_mlp; dst = wmlp_bf; }
        const float4 v = ((const float4*)src)[i];
        bf16x4 o;
        o[0] = (__bf16)v.x; o[1] = (__bf16)v.y; o[2] = (__bf16)v.z; o[3] = (__bf16)v.w;
        ((bf16x4*)dst)[i] = o;
    } else if (bid < NB_CVT + NB_TC) {
        // transpose+convert w_out -> woutT_bf[k][m]
        const int b2 = bid - NB_CVT;
        const int m0 = (b2 >> 3) * 64, k0 = (b2 & 7) * 64;
        const int row = tid >> 2, c4 = (tid & 3) * 16;
        #pragma unroll
        for (int i = 0; i < 4; i++) {
            const float4 v = *(const float4*)&w_out[(size_t)(m0 + row) * EDIM + k0 + c4 + i * 4];
            T[row][c4 + i * 4 + 0] = v.x;
            T[row][c4 + i * 4 + 1] = v.y;
            T[row][c4 + i * 4 + 2] = v.z;
            T[row][c4 + i * 4 + 3] = v.w;
        }
        __syncthreads();
        const int kr = tid >> 2, m16 = (tid & 3) * 16;
        bf16x8 o0, o1;
        #pragma unroll
        for (int i = 0; i < 8; i++) o0[i] = (__bf16)T[m16 + i][kr];
        #pragma unroll
        for (int i = 0; i < 8; i++) o1[i] = (__bf16)T[m16 + 8 + i][kr];
        *(bf16x8*)&woutT_bf[(size_t)(k0 + kr) * EDIM + m0 + m16] = o0;
        *(bf16x8*)&woutT_bf[(size_t)(k0 + kr) * EDIM + m0 + m16 + 8] = o1;
    } else if (bid < NB_CVT + NB_TC + NB_ADD) {
        // add2[m][j] = status[m] . w_mlp[j,512:640] + (mlp_b[j] + w_mlp[j,:512].out_b)
        const int j = (bid - NB_CVT - NB_TC) * 4 + (tid >> 6);
        const int lane = tid & 63;
        const float* wr = w_mlp + (size_t)j * LDCOMB;
        const int k8 = lane * 8;
        const float4 wa = *(const float4*)&wr[k8], wb = *(const float4*)&wr[k8 + 4];
        const float4 oa = *(const float4*)&out_b[k8], ob = *(const float4*)&out_b[k8 + 4];
        float b = wa.x * oa.x + wa.y * oa.y + wa.z * oa.z + wa.w * oa.w +
                  wb.x * ob.x + wb.y * ob.y + wb.z * ob.z + wb.w * ob.w;
        const int c2 = lane * 2;
        const float w0 = wr[EDIM + c2], w1 = wr[EDIM + c2 + 1];
        float s0 = status[c2] * w0 + status[c2 + 1] * w1;
        float s1 = status[128 + c2] * w0 + status[129 + c2] * w1;
        #pragma unroll
        for (int m = 1; m < 64; m <<= 1) {
            b += __shfl_xor(b, m);
            s0 += __shfl_xor(s0, m);
            s1 += __shfl_xor(s1, m);
        }
        if (lane == 0) {
            const float bb = b + mlp_b[j];
            add2[j] = s0 + bb;
            add2[EDIM + j] = s1 + bb;
        }
    } else if (bid < NB_CVT + NB_TC + NB_ADD + NB_TV) {
        // tv[st][j] = time_enc[st] . w_mlp[j,640:896]  (fp32 exact)
        const int b2 = bid - NB_CVT - NB_TC - NB_ADD;
        const int st = b2 >> 1, jg = b2 & 1;
        if (tid < 128) {
            const float div = expf((float)(2 * tid) * (-9.210340371976184f / 256.0f));
            const float ang = (float)st * div;
            sn[tid] = sinf(ang);
            cs[tid] = cosf(ang);
        }
        __syncthreads();
        const int j = jg * 256 + tid;
        const float* wr = w_mlp + (size_t)j * LDCOMB + 640;
        float acc = 0.f;
        #pragma unroll 4
        for (int p = 0; p < 128; p++)
            acc += sn[p] * wr[2 * p] + cs[p] * wr[2 * p + 1];
        tv[st * EDIM + j] = acc;
    } else {
        // counting sort by step + zero work counter
        if (tid == 0) workctr[0] = 0;
        if (tid < NBIN) hist[tid] = 0;
        __syncthreads();
        for (int i = tid; i < N_TOK; i += 256)
            atomicAdd(&hist[min(max(steps[i], 0), NBIN - 1)], 1);
        __syncthreads();
        if (tid == 0) {
            int acc = 0;
            for (int s = 0; s < NBIN; s++) { offs[s] = acc; acc += hist[s]; }
        }
        __syncthreads();
        if (tid < NBIN) bin_start[tid] = offs[tid];
        __syncthreads();
        for (int i = tid; i < N_TOK; i += 256) {
            const int s = min(max(steps[i], 0), NBIN - 1);
            const int pos = atomicAdd(&offs[s], 1);
            perm[pos] = i;
            sstep[pos] = s;
        }
    }
}

// ---------------- merged GEMM launch: qkv (384 blocks) + weff (16 blocks) ----------------
__global__ __launch_bounds__(256) void gemm2_kernel(const __bf16* __restrict__ x_bf,
                                                    const __bf16* __restrict__ wqkv_bf,
                                                    const float* __restrict__ b_in,
                                                    __bf16* __restrict__ qkv_bf,
                                                    const __bf16* __restrict__ wmlp_bf,
                                                    const __bf16* __restrict__ woutT_bf,
                                                    __bf16* __restrict__ weff_bf) {
    __shared__ __attribute__((aligned(16))) __bf16 As[128][40];
    __shared__ __attribute__((aligned(16))) __bf16 Bs[128][40];
    const int bid = blockIdx.x;
    const __bf16 *A, *B;
    const float* bias;
    __bf16* C;
    int lda, ldb, ldc, bm, bn;
    if (bid < 384) {
        A = x_bf; lda = EDIM; B = wqkv_bf; ldb = EDIM; bias = b_in;
        C = qkv_bf; ldc = LDQKV;
        bm = (bid & 31) * 128; bn = (bid >> 5) * 128;
    } else {
        const int b2 = bid - 384;
        A = wmlp_bf; lda = LDCOMB; B = woutT_bf; ldb = EDIM; bias = nullptr;
        C = weff_bf; ldc = EDIM;
        bm = (b2 & 3) * 128; bn = (b2 >> 2) * 128;
    }
    const int tid = threadIdx.x;
    const int wave = tid >> 6, lane = tid & 63;
    const int wm = (wave >> 1) * 64, wn = (wave & 1) * 64;
    const int lr = lane & 15, lq = lane >> 4;

    f32x4 acc[4][4] = {};

    for (int k0 = 0; k0 < EDIM; k0 += 32) {
        __syncthreads();
        #pragma unroll
        for (int c = tid; c < 512; c += 256) {
            const int row = c >> 2, k8 = (c & 3) * 8;
            *(bf16x8*)&As[row][k8] = *(const bf16x8*)&A[(size_t)(bm + row) * lda + k0 + k8];
            *(bf16x8*)&Bs[row][k8] = *(const bf16x8*)&B[(size_t)(bn + row) * ldb + k0 + k8];
        }
        __syncthreads();
        bf16x8 af[4], bfr[4];
        #pragma unroll
        for (int i = 0; i < 4; i++) {
            af[i]  = *(const bf16x8*)&As[wm + i * 16 + lr][lq * 8];
            bfr[i] = *(const bf16x8*)&Bs[wn + i * 16 + lr][lq * 8];
        }
        #pragma unroll
        for (int i = 0; i < 4; i++)
            #pragma unroll
            for (int j = 0; j < 4; j++)
                acc[i][j] = __builtin_amdgcn_mfma_f32_16x16x32_bf16(af[i], bfr[j], acc[i][j], 0, 0, 0);
    }

    #pragma unroll
    for (int i = 0; i < 4; i++) {
        #pragma unroll
        for (int j = 0; j < 4; j++) {
            const int col = bn + wn + j * 16 + lr;
            const float bv = bias ? bias[col] : 0.f;
            #pragma unroll
            for (int r = 0; r < 4; r++) {
                const int row = bm + wm + i * 16 + lq * 4 + r;
                C[(size_t)row * ldc + col] = (__bf16)(acc[i][j][r] + bv);
            }
        }
    }
}

// ---------------- gather sorted Q (prescaled), K compact, V^T ----------------
__global__ __launch_bounds__(256) void gather_kernel(const __bf16* __restrict__ qkv,
                                                     const int* __restrict__ perm,
                                                     __bf16* __restrict__ qs,
                                                     __bf16* __restrict__ ks,
                                                     __bf16* __restrict__ vt) {
    __shared__ __attribute__((aligned(16))) __bf16 T[64][72];
    __shared__ int pr[64];
    const int h = blockIdx.y;
    const int n0 = blockIdx.x * 64;
    const int tid = threadIdx.x;
    if (tid < 64) pr[tid] = perm[n0 + tid];
    __syncthreads();
    const float SC = 0.125f * 1.44269504f;   // 1/sqrt(64) * log2(e)
    #pragma unroll
    for (int c = tid; c < 512; c += 256) {
        const int r = c >> 3, d8 = (c & 7) * 8;
        const size_t src = (size_t)pr[r] * LDQKV + h * HD + d8;
        bf16x8 q = *(const bf16x8*)&qkv[src];
        #pragma unroll
        for (int j = 0; j < 8; j++) q[j] = (__bf16)((float)q[j] * SC);
        *(bf16x8*)&qs[(size_t)(n0 + r) * EDIM + h * HD + d8] = q;
        *(bf16x8*)&ks[(size_t)(n0 + r) * EDIM + h * HD + d8] =
            *(const bf16x8*)&qkv[src + EDIM];
        *(bf16x8*)&T[r][d8] = *(const bf16x8*)&qkv[src + 2 * EDIM];
    }
    __syncthreads();
    #pragma unroll
    for (int c = tid; c < 512; c += 256) {
        const int d = c & 63, k8 = (c >> 6) * 8;
        bf16x8 v;
        #pragma unroll
        for (int j = 0; j < 8; j++) v[j] = T[k8 + j][d];
        *(bf16x8*)&vt[(size_t)(h * HD + d) * N_TOK + n0 + k8] = v;
    }
}

// ---------------- persistent flash attention: work-queue over (qtile, h, ck) ----------------
// 1280 blocks (5/CU by LDS); items handed out largest-first via atomic counter.
__global__ __launch_bounds__(256) void attn_kernel(const __bf16* __restrict__ qs,
                                                   const __bf16* __restrict__ ks,
                                                   const __bf16* __restrict__ vt,
                                                   const int* __restrict__ sstep,
                                                   const int* __restrict__ bin_start,
                                                   __bf16* __restrict__ po,
                                                   float* __restrict__ pl,
                                                   int* __restrict__ workctr) {
    __shared__ __attribute__((aligned(16))) __bf16 Ks[BK][72];     // [key][d]
    __shared__ __attribute__((aligned(16))) __bf16 Vs[64][BK + 8]; // [d][key]
    __shared__ __attribute__((aligned(16))) __bf16 Ps[64][BK + 8]; // [q][key] wave bands
    __shared__ int item_s;

    const int tid = threadIdx.x, wave = tid >> 6, lane = tid & 63;
    const int lr = lane & 15, lq = lane >> 4;
    const int r0 = tid >> 3, r1 = r0 + 32, k8 = (tid & 7) * 8;

    for (;;) {
        __syncthreads();
        if (tid == 0) item_s = atomicAdd(workctr, 1);
        __syncthreads();
        const int item = item_s;
        if (item >= NWORK) return;

        const int qtile = item >> 6;          // ascending qtile = descending work (LPT)
        const int h = (item >> 3) & 7;
        const int ck = item & 7;
        const int qbase = qtile * 64 + wave * 16;

        const int kt0 = bin_start[sstep[qtile * 64]] & ~(BK - 1);
        const int nt = (N_TOK - kt0) / BK;
        const int kta = kt0 + ((nt * ck) / SPLITK) * BK;
        const int ktb = kt0 + ((nt * (ck + 1)) / SPLITK) * BK;
        const int bs_blockmax = bin_start[sstep[qtile * 64 + 63]];

        bf16x8 aq[2];
        {
            const __bf16* qrow = qs + (size_t)(qbase + lr) * EDIM + h * HD;
            aq[0] = *(const bf16x8*)&qrow[lq * 8];
            aq[1] = *(const bf16x8*)&qrow[32 + lq * 8];
        }
        int bs_r[4];
        #pragma unroll
        for (int r = 0; r < 4; r++) bs_r[r] = bin_start[sstep[qbase + lq * 4 + r]];

        float l_i[4] = {0.f, 0.f, 0.f, 0.f};
        f32x4 o[4] = {};

        const __bf16* kbase = ks + h * HD;
        const __bf16* vbase = vt + (size_t)h * HD * N_TOK;

        bf16x8 kr0, kr1, vr0, vr1;
        if (kta < ktb) {
            kr0 = *(const bf16x8*)&kbase[(size_t)(kta + r0) * EDIM + k8];
            kr1 = *(const bf16x8*)&kbase[(size_t)(kta + r1) * EDIM + k8];
            vr0 = *(const bf16x8*)&vbase[(size_t)r0 * N_TOK + kta + k8];
            vr1 = *(const bf16x8*)&vbase[(size_t)r1 * N_TOK + kta + k8];
        }

        for (int kt = kta; kt < ktb; kt += BK) {
            __syncthreads();
            *(bf16x8*)&Ks[r0][k8] = kr0;
            *(bf16x8*)&Ks[r1][k8] = kr1;
            *(bf16x8*)&Vs[r0][k8] = vr0;
            *(bf16x8*)&Vs[r1][k8] = vr1;
            __syncthreads();
            if (kt + BK < ktb) {
                kr0 = *(const bf16x8*)&kbase[(size_t)(kt + BK + r0) * EDIM + k8];
                kr1 = *(const bf16x8*)&kbase[(size_t)(kt + BK + r1) * EDIM + k8];
                vr0 = *(const bf16x8*)&vbase[(size_t)r0 * N_TOK + kt + BK + k8];
                vr1 = *(const bf16x8*)&vbase[(size_t)r1 * N_TOK + kt + BK + k8];
            }

            f32x4 s[4];
            #pragma unroll
            for (int t = 0; t < 4; t++) {
                bf16x8 b0 = *(const bf16x8*)&Ks[t * 16 + lr][lq * 8];
                bf16x8 b1 = *(const bf16x8*)&Ks[t * 16 + lr][32 + lq * 8];
                f32x4 a = {};
                a = __builtin_amdgcn_mfma_f32_16x16x32_bf16(aq[0], b0, a, 0, 0, 0);
                a = __builtin_amdgcn_mfma_f32_16x16x32_bf16(aq[1], b1, a, 0, 0, 0);
                s[t] = a;
            }
            if (kt < bs_blockmax) {
                #pragma unroll
                for (int t = 0; t < 4; t++) {
                    const int col = kt + t * 16 + lr;
                    #pragma unroll
                    for (int r = 0; r < 4; r++)
                        if (col < bs_r[r]) s[t][r] = -1e9f;
                }
            }
            #pragma unroll
            for (int t = 0; t < 4; t++) {
                #pragma unroll
                for (int r = 0; r < 4; r++) {
                    const float p = exp2f(s[t][r]);
                    l_i[r] += p;
                    Ps[wave * 16 + lq * 4 + r][t * 16 + lr] = (__bf16)p;
                }
            }
            #pragma unroll
            for (int ks2 = 0; ks2 < 2; ks2++) {
                bf16x8 ap = *(const bf16x8*)&Ps[wave * 16 + lr][ks2 * 32 + lq * 8];
                #pragma unroll
                for (int dt = 0; dt < 4; dt++) {
                    bf16x8 bv = *(const bf16x8*)&Vs[dt * 16 + lr][ks2 * 32 + lq * 8];
                    o[dt] = __builtin_amdgcn_mfma_f32_16x16x32_bf16(ap, bv, o[dt], 0, 0, 0);
                }
            }
        }

        #pragma unroll
        for (int r = 0; r < 4; r++) {
            float v = l_i[r];
            v += __shfl_xor(v, 1);
            v += __shfl_xor(v, 2);
            v += __shfl_xor(v, 4);
            v += __shfl_xor(v, 8);
            l_i[r] = v;
        }
        __bf16* pob = po + (((size_t)(ck * NHEAD + h) * N_TOK) + qbase) * HD;
        #pragma unroll
        for (int dt = 0; dt < 4; dt++)
            #pragma unroll
            for (int r = 0; r < 4; r++)
                pob[(lq * 4 + r) * HD + dt * 16 + lr] = (__bf16)o[dt][r];
        if (lr == 0) {
            #pragma unroll
            for (int r = 0; r < 4; r++)
                pl[(size_t)(ck * NHEAD + h) * N_TOK + qbase + lq * 4 + r] = l_i[r];
        }
    }
}

// ---------------- combine split-K partials, normalize, scatter to ctx ----------------
__global__ __launch_bounds__(256) void combine_kernel(const __bf16* __restrict__ po,
                                                      const float* __restrict__ pl,
                                                      const int* __restrict__ perm,
                                                      __bf16* __restrict__ ctx) {
    const int e = blockIdx.x * 256 + threadIdx.x;   // over 4096*512
    const int q = e >> 9;
    const int col = e & 511;
    const int h = col >> 6, d = col & 63;
    float s = 0.f, l = 0.f;
    #pragma unroll
    for (int c = 0; c < SPLITK; c++) {
        s += (float)po[(((size_t)(c * NHEAD + h) * N_TOK) + q) * HD + d];
        l += pl[(size_t)(c * NHEAD + h) * N_TOK + q];
    }
    ctx[(size_t)perm[q] * EDIM + col] = (__bf16)(s / l);
}

// ---------------- fused final GEMM: h = ctx @ weff^T + add2[dmask] + tv[step] ----------------
__global__ __launch_bounds__(256) void gemm_fused(const __bf16* __restrict__ A,
                                                  const __bf16* __restrict__ B,
                                                  const int* __restrict__ dmask,
                                                  const int* __restrict__ steps,
                                                  const float* __restrict__ add2,
                                                  const float* __restrict__ tv,
                                                  float* __restrict__ C) {
    __shared__ __attribute__((aligned(16))) __bf16 As[128][40];
    __shared__ __attribute__((aligned(16))) __bf16 Bs[128][40];
    const int tid = threadIdx.x;
    const int wave = tid >> 6, lane = tid & 63;
    const int wm = (wave >> 1) * 64, wn = (wave & 1) * 64;
    const int bm = blockIdx.x * 128, bn = blockIdx.y * 128;
    const int lr = lane & 15, lq = lane >> 4;

    f32x4 acc[4][4] = {};

    for (int k0 = 0; k0 < EDIM; k0 += 32) {
        __syncthreads();
        #pragma unroll
        for (int c = tid; c < 512; c += 256) {
            const int row = c >> 2, k8 = (c & 3) * 8;
            *(bf16x8*)&As[row][k8] = *(const bf16x8*)&A[(size_t)(bm + row) * EDIM + k0 + k8];
            *(bf16x8*)&Bs[row][k8] = *(const bf16x8*)&B[(size_t)(bn + row) * EDIM + k0 + k8];
        }
        __syncthreads();
        bf16x8 af[4], bfr[4];
        #pragma unroll
        for (int i = 0; i < 4; i++) {
            af[i]  = *(const bf16x8*)&As[wm + i * 16 + lr][lq * 8];
            bfr[i] = *(const bf16x8*)&Bs[wn + i * 16 + lr][lq * 8];
        }
        #pragma unroll
        for (int i = 0; i < 4; i++)
            #pragma unroll
            for (int j = 0; j < 4; j++)
                acc[i][j] = __builtin_amdgcn_mfma_f32_16x16x32_bf16(af[i], bfr[j], acc[i][j], 0, 0, 0);
    }

    int dmr[4][4], str[4][4];
    #pragma unroll
    for (int i = 0; i < 4; i++)
        #pragma unroll
        for (int r = 0; r < 4; r++) {
            const int row = bm + wm + i * 16 + lq * 4 + r;
            dmr[i][r] = dmask[row];
            str[i][r] = min(max(steps[row], 0), NBIN - 1);
        }
    #pragma unroll
    for (int i = 0; i < 4; i++) {
        #pragma unroll
        for (int j = 0; j < 4; j++) {
            const int col = bn + wn + j * 16 + lr;
            #pragma unroll
            for (int r = 0; r < 4; r++) {
                const int row = bm + wm + i * 16 + lq * 4 + r;
                const float v = acc[i][j][r] + add2[dmr[i][r] * EDIM + col]
                              + tv[str[i][r] * EDIM + col];
                C[(size_t)row * EDIM + col] = v;
            }
        }
    }
}

// ---------------- LayerNorm + ReLU + residual ----------------
__global__ __launch_bounds__(256) void ln_kernel(const float* __restrict__ h,
                                                 const float* __restrict__ x,
                                                 const float* __restrict__ gamma,
                                                 const float* __restrict__ beta,
                                                 float* __restrict__ out) {
    const int row = blockIdx.x * 4 + (threadIdx.x >> 6);
    const int lane = threadIdx.x & 63;
    const float* hr = h + (size_t)row * EDIM;
    float4 v0 = ((const float4*)hr)[lane];
    float4 v1 = ((const float4*)hr)[64 + lane];
    float sum = v0.x + v0.y + v0.z + v0.w + v1.x + v1.y + v1.z + v1.w;
    float sq = v0.x * v0.x + v0.y * v0.y + v0.z * v0.z + v0.w * v0.w +
               v1.x * v1.x + v1.y * v1.y + v1.z * v1.z + v1.w * v1.w;
    #pragma unroll
    for (int m = 1; m < 64; m <<= 1) {
        sum += __shfl_xor(sum, m);
        sq  += __shfl_xor(sq, m);
    }
    const float mean = sum * (1.0f / EDIM);
    const float var = sq * (1.0f / EDIM) - mean * mean;
    const float rstd = rsqrtf(var + 1e-5f);
    const float* xr = x + (size_t)row * EDIM;
    float* orow = out + (size_t)row * EDIM;
    #pragma unroll
    for (int half = 0; half < 2; half++) {
        const float4 v = half ? v1 : v0;
        const int cb = half * 256 + lane * 4;
        float4 res;
        const float* vp = (const float*)&v;
        float tmp[4];
        #pragma unroll
        for (int i = 0; i < 4; i++) {
            const int c = cb + i;
            float t = (vp[i] - mean) * rstd * gamma[c] + beta[c];
            t = fmaxf(t, 0.f);
            tmp[i] = xr[c] + t;
        }
        res.x = tmp[0]; res.y = tmp[1]; res.z = tmp[2]; res.w = tmp[3];
        ((float4*)orow)[cb >> 2] = res;
    }
}

// ---------------- launch ----------------
extern "C" void kernel_launch(void* const* d_in, const int* in_sizes, int n_in,
                              void* d_out, int out_size, void* d_ws, size_t ws_size,
                              hipStream_t stream) {
    const float* x      = (const float*)d_in[0];
    const int*   dmask  = (const int*)d_in[1];
    const int*   steps  = (const int*)d_in[2];
    const float* status = (const float*)d_in[3];
    const float* w_in   = (const float*)d_in[4];
    const float* b_in   = (const float*)d_in[5];
    const float* w_out  = (const float*)d_in[6];
    const float* b_out  = (const float*)d_in[7];
    const float* w_mlp  = (const float*)d_in[8];
    const float* b_mlp  = (const float*)d_in[9];
    const float* gamma  = (const float*)d_in[10];
    const float* beta   = (const float*)d_in[11];
    float* out = (float*)d_out;

    char* ws = (char*)d_ws;
    size_t off = 0;
    auto alloc = [&](size_t bytes) {
        void* p = ws + off;
        off = (off + bytes + 255) & ~(size_t)255;
        return p;
    };
    __bf16* x_bf    = (__bf16*)alloc((size_t)N_TOK * EDIM * 2);   // reused as qs
    __bf16* wqkv_bf = (__bf16*)alloc((size_t)3 * EDIM * EDIM * 2);
    __bf16* wmlp_bf = (__bf16*)alloc((size_t)EDIM * LDCOMB * 2);
    __bf16* woutT_bf= (__bf16*)alloc((size_t)EDIM * EDIM * 2);
    __bf16* weff_bf = (__bf16*)alloc((size_t)EDIM * EDIM * 2);
    __bf16* qkv_bf  = (__bf16*)alloc((size_t)N_TOK * LDQKV * 2);
    __bf16* ks_bf   = (__bf16*)alloc((size_t)N_TOK * EDIM * 2);
    __bf16* vt_bf   = (__bf16*)alloc((size_t)EDIM * N_TOK * 2);
    __bf16* ctx_bf  = (__bf16*)alloc((size_t)N_TOK * EDIM * 2);
    float*  h_f32   = (float*)alloc((size_t)N_TOK * EDIM * 4);
    int*    perm    = (int*)alloc(N_TOK * 4);
    int*    sstep   = (int*)alloc(N_TOK * 4);
    int*    binst   = (int*)alloc(NBIN * 4);
    __bf16* po      = (__bf16*)alloc((size_t)SPLITK * NHEAD * N_TOK * HD * 2);
    float*  pl      = (float*)alloc((size_t)SPLITK * NHEAD * N_TOK * 4);
    float*  add2    = (float*)alloc(2 * EDIM * 4);
    float*  tv      = (float*)alloc((size_t)NBIN * EDIM * 4);
    int*    workctr = (int*)alloc(256);
    __bf16* qs_bf   = x_bf;   // alias: x_bf dead after qkv GEMM

    // prep: converts + w_out transpose + add2 + tv + sort + counter zero
    prep_kernel<<<NB_PREP, 256, 0, stream>>>(
        x, w_in, w_mlp, w_out, status, b_out, b_mlp, steps,
        x_bf, wqkv_bf, wmlp_bf, woutT_bf, add2, tv, perm, sstep, binst, workctr);
    // qkv GEMM + weff GEMM (merged launch)
    gemm2_kernel<<<400, 256, 0, stream>>>(
        x_bf, wqkv_bf, b_in, qkv_bf, wmlp_bf, woutT_bf, weff_bf);
    // gather sorted Q/K/V^T
    gather_kernel<<<dim3(N_TOK / 64, NHEAD), 256, 0, stream>>>(qkv_bf, perm, qs_bf, ks_bf, vt_bf);
    // persistent attention
    attn_kernel<<<1280, 256, 0, stream>>>(qs_bf, ks_bf, vt_bf, sstep, binst, po, pl, workctr);
    // combine partials -> ctx (original token order)
    combine_kernel<<<(N_TOK * EDIM) / 256, 256, 0, stream>>>(po, pl, perm, ctx_bf);
    // h = ctx @ w_eff^T + add2[dmask] + tv[step]
    gemm_fused<<<dim3(N_TOK / 128, EDIM / 128), 256, 0, stream>>>(
        ctx_bf, weff_bf, dmask, steps, add2, tv, h_f32);
    // LN + ReLU + residual
    ln_kernel<<<N_TOK / 4, 256, 0, stream>>>(h_f32, x, gamma, beta, out);
}